// Round 8
// baseline (275.282 us; speedup 1.0000x reference)
//
#include <hip/hip_runtime.h>
#include <math.h>

// SimpleInfoNCE: N=8192 (2048 groups of 4), D=256, T=0.5.
// normalize -> bf16 hi/lo split (16x8-chunk layout) -> symmetric triangle MFMA
// GEMM (128^2 tiles, 16x16x32, 3-buffer counted-vmcnt) with fused exp + masked
// sums + last-block log/mean reduction.
#define NROW 8192
#define DIM 256
#define NTILE 64            // 8192 / 128
#define NBLK 2080           // NTILE*(NTILE+1)/2 upper-triangle tiles
#define NT 24               // 3 passes (HiHi,HiLo,LoHi) x 8 steps of K=32

typedef float f32x4  __attribute__((ext_vector_type(4)));
typedef short short8 __attribute__((ext_vector_type(8)));

__device__ __forceinline__ ushort f2bf_rne(float x) {
    unsigned u = __float_as_uint(x);
    unsigned r = (u + 0x7FFFu + ((u >> 16) & 1u)) >> 16;
    return (ushort)r;
}
__device__ __forceinline__ float bf2f(ushort h) {
    return __uint_as_float(((unsigned)h) << 16);
}

// 32 rows per block. Coalesced float4 loads, per-wave norm, LDS layout
// transform, fully coalesced chunked stores of the 16x8-chunk layout:
//   ushort_idx(row,k) = ((row>>4)*32 + (k>>3))*128 + (row&15)*8 + (k&7)
// (rows 32b..32b+31 occupy the contiguous global range [b*8192,(b+1)*8192)).
// Also zeroes all_sum/pos_sum (64 floats per block) and the done counter.
__global__ __launch_bounds__(256) void prep_kernel(const float* __restrict__ f,
                                                   ushort* __restrict__ Hi,
                                                   ushort* __restrict__ Lo,
                                                   float* __restrict__ sums,
                                                   unsigned* __restrict__ done) {
    __shared__ ushort hbuf[8192];
    __shared__ ushort lbuf[8192];
    const int tid = threadIdx.x;
    if (tid < 64) sums[blockIdx.x * 64 + tid] = 0.0f;
    if (blockIdx.x == 0 && tid == 0) *done = 0u;
    const int w = tid >> 6, l = tid & 63;
    const int r0 = blockIdx.x * 32;
#pragma unroll
    for (int it = 0; it < 8; ++it) {
        const int rl = it * 4 + w;                       // row_local 0..31
        float4 v = reinterpret_cast<const float4*>(f + (size_t)(r0 + rl) * DIM)[l];
        float ss = v.x * v.x + v.y * v.y + v.z * v.z + v.w * v.w;
#pragma unroll
        for (int m = 32; m; m >>= 1) ss += __shfl_xor(ss, m, 64);
        const float inv = 1.0f / sqrtf(ss);
        float xv[4] = {v.x * inv, v.y * inv, v.z * inv, v.w * inv};
        ushort hv[4], lv[4];
#pragma unroll
        for (int i = 0; i < 4; ++i) {
            hv[i] = f2bf_rne(xv[i]);
            lv[i] = f2bf_rne(xv[i] - bf2f(hv[i]));
        }
        // k0 = 4l: k>>3 = l>>1, k&7 = (l&1)*4
        const int pos = (rl >> 4) * 4096 + (l >> 1) * 128 + (rl & 15) * 8 + (l & 1) * 4;
        *reinterpret_cast<ushort4*>(&hbuf[pos]) = make_ushort4(hv[0], hv[1], hv[2], hv[3]);
        *reinterpret_cast<ushort4*>(&lbuf[pos]) = make_ushort4(lv[0], lv[1], lv[2], lv[3]);
    }
    __syncthreads();
    const size_t gbase = (size_t)blockIdx.x * 8192;
#pragma unroll
    for (int it = 0; it < 8; ++it) {
        const int o = it * 1024 + tid * 4;
        *reinterpret_cast<ushort4*>(&Hi[gbase + o]) = *reinterpret_cast<const ushort4*>(&hbuf[o]);
        *reinterpret_cast<ushort4*>(&Lo[gbase + o]) = *reinterpret_cast<const ushort4*>(&lbuf[o]);
    }
}

__device__ __forceinline__ void gload16(const void* g, void* lp) {
    __builtin_amdgcn_global_load_lds((__attribute__((address_space(1))) void*)g,
                                     (__attribute__((address_space(3))) void*)lp, 16, 0, 0);
}

// 128x128 tile per 256-thread block (4 waves, each 64x64 = 4x4 frags of
// 16x16x32). 3-buffer counted-vmcnt pipeline (proven R4 skeleton):
//   tile t in buf[t%3]; stage t+2 during t; vmcnt(4) + one barrier per step.
// Last block to finish runs the log/mean reduction (done-counter pattern).
__global__ __launch_bounds__(256, 3) void infonce_mfma(const ushort* __restrict__ Hi,
                                                       const ushort* __restrict__ Lo,
                                                       float* __restrict__ all_sum,
                                                       float* __restrict__ pos_sum,
                                                       unsigned* __restrict__ done,
                                                       float* __restrict__ out) {
    __shared__ ushort lds[3][2][4096];   // 3 bufs x (A,B) x 8KB = 48KB
    __shared__ float red[4];
    __shared__ bool lastBlock;

    // XCD swizzle (2080 = 8*260, bijective), then unrank -> upper triangle
    const int swz = (blockIdx.x & 7) * 260 + (blockIdx.x >> 3);
    int ti = 0, rem = swz;
    while (rem >= NTILE - ti) { rem -= NTILE - ti; ++ti; }
    const int tj = ti + rem;

    const int tid = threadIdx.x;
    const int wid = tid >> 6, l = tid & 63;
    const int wr = wid >> 1, wc = wid & 1;

    f32x4 acc[4][4];
#pragma unroll
    for (int m = 0; m < 4; ++m)
#pragma unroll
        for (int n = 0; n < 4; ++n) acc[m][n] = (f32x4){0.f, 0.f, 0.f, 0.f};

#define STAGE(bufi, t) do {                                                             \
        const int pass_ = (t) >> 3, kk_ = (t) & 7;                                      \
        const ushort* As_ = (pass_ == 2) ? Lo : Hi;                                     \
        const ushort* Bs_ = (pass_ == 1) ? Lo : Hi;                                     \
        const int f0_ = wid * 2, f1_ = f0_ + 1;                                         \
        gload16(&As_[(size_t)((ti * 8 + f0_) * 4096 + kk_ * 512) + l * 8],              \
                &lds[bufi][0][f0_ * 512 + l * 8]);                                      \
        gload16(&As_[(size_t)((ti * 8 + f1_) * 4096 + kk_ * 512) + l * 8],              \
                &lds[bufi][0][f1_ * 512 + l * 8]);                                      \
        gload16(&Bs_[(size_t)((tj * 8 + f0_) * 4096 + kk_ * 512) + l * 8],              \
                &lds[bufi][1][f0_ * 512 + l * 8]);                                      \
        gload16(&Bs_[(size_t)((tj * 8 + f1_) * 4096 + kk_ * 512) + l * 8],              \
                &lds[bufi][1][f1_ * 512 + l * 8]);                                      \
    } while (0)

#define VWAIT(n) asm volatile("s_waitcnt vmcnt(" #n ")" ::: "memory")

#define BODY(t, bR, bS, DOSTG, W) do {                                                  \
        short8 af_[4], bf_[4];                                                          \
        _Pragma("unroll") for (int m = 0; m < 4; ++m)                                   \
            af_[m] = *reinterpret_cast<const short8*>(&lds[bR][0][(wr * 4 + m) * 512 + l * 8]); \
        _Pragma("unroll") for (int n = 0; n < 4; ++n)                                   \
            bf_[n] = *reinterpret_cast<const short8*>(&lds[bR][1][(wc * 4 + n) * 512 + l * 8]); \
        if (DOSTG) STAGE(bS, (t) + 2);                                                  \
        __builtin_amdgcn_s_setprio(1);                                                  \
        _Pragma("unroll") for (int m = 0; m < 4; ++m)                                   \
            _Pragma("unroll") for (int n = 0; n < 4; ++n)                               \
                acc[m][n] = __builtin_amdgcn_mfma_f32_16x16x32_bf16(af_[m], bf_[n], acc[m][n], 0, 0, 0); \
        __builtin_amdgcn_s_setprio(0);                                                  \
        VWAIT(W);                                                                       \
        __builtin_amdgcn_s_barrier();                                                   \
    } while (0)

    STAGE(0, 0);
    STAGE(1, 1);
    VWAIT(4);
    __builtin_amdgcn_s_barrier();

#pragma unroll 1
    for (int tb = 0; tb < 21; tb += 3) {       // t = 0..20
        BODY(tb + 0, 0, 2, 1, 4);
        BODY(tb + 1, 1, 0, 1, 4);
        BODY(tb + 2, 2, 1, 1, 4);
    }
    BODY(21, 0, 2, 1, 4);                      // stages 23 -> buf 2
    BODY(22, 1, 0, 0, 0);
    BODY(23, 2, 0, 0, 0);

    // ---- epilogue: exp + masked sums (C/D: col=lane&15, row=(l>>4)*4+e) ----
    const int rbase = ti * 128 + wr * 64;
    const int cbase = tj * 128 + wc * 64;
    const int h = l >> 4, c16 = l & 15;

    if (ti == tj) {
#pragma unroll
        for (int m = 0; m < 4; ++m)
#pragma unroll
            for (int e = 0; e < 4; ++e) {
                const int row = rbase + m * 16 + h * 4 + e;
                float asum = 0.f, psum = 0.f;
#pragma unroll
                for (int n = 0; n < 4; ++n) {
                    const int col = cbase + n * 16 + c16;
                    float v = __expf(2.0f * acc[m][n][e]);
                    v = (row == col) ? 0.f : v;
                    asum += v;
                    psum += ((row >> 2) == (col >> 2)) ? v : 0.f;
                }
#pragma unroll
                for (int mk = 1; mk < 16; mk <<= 1) {
                    asum += __shfl_xor(asum, mk, 64);
                    psum += __shfl_xor(psum, mk, 64);
                }
                if (c16 == 0) {
                    atomicAdd(&all_sum[row], asum);
                    atomicAdd(&pos_sum[row], psum);
                }
            }
    } else {
        float csum[4] = {0.f, 0.f, 0.f, 0.f};
#pragma unroll
        for (int m = 0; m < 4; ++m)
#pragma unroll
            for (int e = 0; e < 4; ++e) {
                const int row = rbase + m * 16 + h * 4 + e;
                float asum = 0.f;
#pragma unroll
                for (int n = 0; n < 4; ++n) {
                    float v = __expf(2.0f * acc[m][n][e]);
                    asum += v;
                    csum[n] += v;
                }
#pragma unroll
                for (int mk = 1; mk < 16; mk <<= 1) asum += __shfl_xor(asum, mk, 64);
                if (c16 == 0) atomicAdd(&all_sum[row], asum);
            }
#pragma unroll
        for (int n = 0; n < 4; ++n) {
            float cs = csum[n];
            cs += __shfl_xor(cs, 16, 64);
            cs += __shfl_xor(cs, 32, 64);
            if (h == 0) atomicAdd(&all_sum[cbase + n * 16 + c16], cs);
        }
    }

    // ---- fused loss: last finished block reduces log(all)-log(pos) ----
    __threadfence();                       // release: this block's atomics visible
    if (tid == 0) {
        unsigned old = atomicAdd(done, 1u);
        lastBlock = (old == NBLK - 1);
    }
    __syncthreads();
    if (lastBlock) {
        __threadfence();                   // acquire: see all blocks' sums
        float s = 0.0f;
#pragma unroll 4
        for (int i = tid; i < NROW; i += 256)
            s += __logf(all_sum[i]) - __logf(pos_sum[i]);
#pragma unroll
        for (int off = 32; off; off >>= 1) s += __shfl_xor(s, off, 64);
        if (l == 0) red[wid] = s;
        __syncthreads();
        if (tid == 0) out[0] = (red[0] + red[1] + red[2] + red[3]) / (float)NROW;
    }
#undef STAGE
#undef VWAIT
#undef BODY
}

extern "C" void kernel_launch(void* const* d_in, const int* in_sizes, int n_in,
                              void* d_out, int out_size, void* d_ws, size_t ws_size,
                              hipStream_t stream) {
    const float* f = (const float*)d_in[0];
    float* out = (float*)d_out;

    float*    all_sum = (float*)d_ws;                  // 8192 f32
    float*    pos_sum = all_sum + NROW;                // 8192 f32
    unsigned* done    = (unsigned*)(pos_sum + NROW);   // 1 u32 (+pad)
    ushort*   Hi      = (ushort*)(pos_sum + NROW + 4); // 8192x256 bf16, chunked
    ushort*   Lo      = Hi + (size_t)NROW * DIM;

    prep_kernel<<<NROW / 32, 256, 0, stream>>>(f, Hi, Lo, all_sum, done);
    infonce_mfma<<<NBLK, 256, 0, stream>>>(Hi, Lo, all_sum, pos_sum, done, out);
}

// Round 9
// 143.631 us; speedup vs baseline: 1.9166x; 1.9166x over previous
//
#include <hip/hip_runtime.h>
#include <math.h>

// SimpleInfoNCE: N=8192 (2048 groups of 4), D=256, T=0.5.
// normalize -> bf16 hi/lo split (16x8-chunk layout) -> symmetric triangle MFMA
// GEMM (128^2 tiles, 16x16x32, 3-buffer counted-vmcnt, XCD swizzle) -> loss.
// NOTE: no __threadfence in the hot kernel — agent fences invalidate XCD L2
// (R8: 3x slowdown). Loss is a separate tiny kernel.
#define NROW 8192
#define DIM 256
#define NTILE 64            // 8192 / 128
#define NBLK 2080           // NTILE*(NTILE+1)/2 upper-triangle tiles
#define NT 24               // 3 passes (HiHi,HiLo,LoHi) x 8 steps of K=32

typedef float f32x4  __attribute__((ext_vector_type(4)));
typedef short short8 __attribute__((ext_vector_type(8)));

__device__ __forceinline__ ushort f2bf_rne(float x) {
    unsigned u = __float_as_uint(x);
    unsigned r = (u + 0x7FFFu + ((u >> 16) & 1u)) >> 16;
    return (ushort)r;
}
__device__ __forceinline__ float bf2f(ushort h) {
    return __uint_as_float(((unsigned)h) << 16);
}

// 32 rows per block. Coalesced float4 loads, per-wave norm, LDS layout
// transform, fully coalesced chunked stores of the 16x8-chunk layout:
//   ushort_idx(row,k) = ((row>>4)*32 + (k>>3))*128 + (row&15)*8 + (k&7)
// Also zeroes all_sum/pos_sum (64 floats per block).
__global__ __launch_bounds__(256) void prep_kernel(const float* __restrict__ f,
                                                   ushort* __restrict__ Hi,
                                                   ushort* __restrict__ Lo,
                                                   float* __restrict__ sums) {
    __shared__ ushort hbuf[8192];
    __shared__ ushort lbuf[8192];
    const int tid = threadIdx.x;
    if (tid < 64) sums[blockIdx.x * 64 + tid] = 0.0f;
    const int w = tid >> 6, l = tid & 63;
    const int r0 = blockIdx.x * 32;
#pragma unroll
    for (int it = 0; it < 8; ++it) {
        const int rl = it * 4 + w;                       // row_local 0..31
        float4 v = reinterpret_cast<const float4*>(f + (size_t)(r0 + rl) * DIM)[l];
        float ss = v.x * v.x + v.y * v.y + v.z * v.z + v.w * v.w;
#pragma unroll
        for (int m = 32; m; m >>= 1) ss += __shfl_xor(ss, m, 64);
        const float inv = 1.0f / sqrtf(ss);
        float xv[4] = {v.x * inv, v.y * inv, v.z * inv, v.w * inv};
        ushort hv[4], lv[4];
#pragma unroll
        for (int i = 0; i < 4; ++i) {
            hv[i] = f2bf_rne(xv[i]);
            lv[i] = f2bf_rne(xv[i] - bf2f(hv[i]));
        }
        // k0 = 4l: k>>3 = l>>1, k&7 = (l&1)*4
        const int pos = (rl >> 4) * 4096 + (l >> 1) * 128 + (rl & 15) * 8 + (l & 1) * 4;
        *reinterpret_cast<ushort4*>(&hbuf[pos]) = make_ushort4(hv[0], hv[1], hv[2], hv[3]);
        *reinterpret_cast<ushort4*>(&lbuf[pos]) = make_ushort4(lv[0], lv[1], lv[2], lv[3]);
    }
    __syncthreads();
    const size_t gbase = (size_t)blockIdx.x * 8192;
#pragma unroll
    for (int it = 0; it < 8; ++it) {
        const int o = it * 1024 + tid * 4;
        *reinterpret_cast<ushort4*>(&Hi[gbase + o]) = *reinterpret_cast<const ushort4*>(&hbuf[o]);
        *reinterpret_cast<ushort4*>(&Lo[gbase + o]) = *reinterpret_cast<const ushort4*>(&lbuf[o]);
    }
}

__device__ __forceinline__ void gload16(const void* g, void* lp) {
    __builtin_amdgcn_global_load_lds((__attribute__((address_space(1))) void*)g,
                                     (__attribute__((address_space(3))) void*)lp, 16, 0, 0);
}

// 128x128 tile per 256-thread block (4 waves, each 64x64 = 4x4 frags of
// 16x16x32). 3-buffer counted-vmcnt pipeline (measured 648 TF, R4):
//   tile t in buf[t%3]; stage t+2 during t; vmcnt(4) + one barrier per step.
__global__ __launch_bounds__(256, 3) void infonce_mfma(const ushort* __restrict__ Hi,
                                                       const ushort* __restrict__ Lo,
                                                       float* __restrict__ all_sum,
                                                       float* __restrict__ pos_sum) {
    __shared__ ushort lds[3][2][4096];   // 3 bufs x (A,B) x 8KB = 48KB

    // XCD swizzle (2080 = 8*260, bijective), then unrank -> upper triangle
    const int swz = (blockIdx.x & 7) * 260 + (blockIdx.x >> 3);
    int ti = 0, rem = swz;
    while (rem >= NTILE - ti) { rem -= NTILE - ti; ++ti; }
    const int tj = ti + rem;

    const int tid = threadIdx.x;
    const int wid = tid >> 6, l = tid & 63;
    const int wr = wid >> 1, wc = wid & 1;

    f32x4 acc[4][4];
#pragma unroll
    for (int m = 0; m < 4; ++m)
#pragma unroll
        for (int n = 0; n < 4; ++n) acc[m][n] = (f32x4){0.f, 0.f, 0.f, 0.f};

#define STAGE(bufi, t) do {                                                             \
        const int pass_ = (t) >> 3, kk_ = (t) & 7;                                      \
        const ushort* As_ = (pass_ == 2) ? Lo : Hi;                                     \
        const ushort* Bs_ = (pass_ == 1) ? Lo : Hi;                                     \
        const int f0_ = wid * 2, f1_ = f0_ + 1;                                         \
        gload16(&As_[(size_t)((ti * 8 + f0_) * 4096 + kk_ * 512) + l * 8],              \
                &lds[bufi][0][f0_ * 512 + l * 8]);                                      \
        gload16(&As_[(size_t)((ti * 8 + f1_) * 4096 + kk_ * 512) + l * 8],              \
                &lds[bufi][0][f1_ * 512 + l * 8]);                                      \
        gload16(&Bs_[(size_t)((tj * 8 + f0_) * 4096 + kk_ * 512) + l * 8],              \
                &lds[bufi][1][f0_ * 512 + l * 8]);                                      \
        gload16(&Bs_[(size_t)((tj * 8 + f1_) * 4096 + kk_ * 512) + l * 8],              \
                &lds[bufi][1][f1_ * 512 + l * 8]);                                      \
    } while (0)

#define VWAIT(n) asm volatile("s_waitcnt vmcnt(" #n ")" ::: "memory")

#define BODY(t, bR, bS, DOSTG, W) do {                                                  \
        short8 af_[4], bf_[4];                                                          \
        _Pragma("unroll") for (int m = 0; m < 4; ++m)                                   \
            af_[m] = *reinterpret_cast<const short8*>(&lds[bR][0][(wr * 4 + m) * 512 + l * 8]); \
        _Pragma("unroll") for (int n = 0; n < 4; ++n)                                   \
            bf_[n] = *reinterpret_cast<const short8*>(&lds[bR][1][(wc * 4 + n) * 512 + l * 8]); \
        if (DOSTG) STAGE(bS, (t) + 2);                                                  \
        __builtin_amdgcn_s_setprio(1);                                                  \
        _Pragma("unroll") for (int m = 0; m < 4; ++m)                                   \
            _Pragma("unroll") for (int n = 0; n < 4; ++n)                               \
                acc[m][n] = __builtin_amdgcn_mfma_f32_16x16x32_bf16(af_[m], bf_[n], acc[m][n], 0, 0, 0); \
        __builtin_amdgcn_s_setprio(0);                                                  \
        VWAIT(W);                                                                       \
        __builtin_amdgcn_s_barrier();                                                   \
    } while (0)

    STAGE(0, 0);
    STAGE(1, 1);
    VWAIT(4);
    __builtin_amdgcn_s_barrier();

#pragma unroll 1
    for (int tb = 0; tb < 21; tb += 3) {       // t = 0..20
        BODY(tb + 0, 0, 2, 1, 4);
        BODY(tb + 1, 1, 0, 1, 4);
        BODY(tb + 2, 2, 1, 1, 4);
    }
    BODY(21, 0, 2, 1, 4);                      // stages 23 -> buf 2
    BODY(22, 1, 0, 0, 0);
    BODY(23, 2, 0, 0, 0);

    // ---- epilogue: exp + masked sums (C/D: col=lane&15, row=(l>>4)*4+e) ----
    const int rbase = ti * 128 + wr * 64;
    const int cbase = tj * 128 + wc * 64;
    const int h = l >> 4, c16 = l & 15;

    if (ti == tj) {
#pragma unroll
        for (int m = 0; m < 4; ++m)
#pragma unroll
            for (int e = 0; e < 4; ++e) {
                const int row = rbase + m * 16 + h * 4 + e;
                float asum = 0.f, psum = 0.f;
#pragma unroll
                for (int n = 0; n < 4; ++n) {
                    const int col = cbase + n * 16 + c16;
                    float v = __expf(2.0f * acc[m][n][e]);
                    v = (row == col) ? 0.f : v;
                    asum += v;
                    psum += ((row >> 2) == (col >> 2)) ? v : 0.f;
                }
#pragma unroll
                for (int mk = 1; mk < 16; mk <<= 1) {
                    asum += __shfl_xor(asum, mk, 64);
                    psum += __shfl_xor(psum, mk, 64);
                }
                if (c16 == 0) {
                    atomicAdd(&all_sum[row], asum);
                    atomicAdd(&pos_sum[row], psum);
                }
            }
    } else {
        float csum[4] = {0.f, 0.f, 0.f, 0.f};
#pragma unroll
        for (int m = 0; m < 4; ++m)
#pragma unroll
            for (int e = 0; e < 4; ++e) {
                const int row = rbase + m * 16 + h * 4 + e;
                float asum = 0.f;
#pragma unroll
                for (int n = 0; n < 4; ++n) {
                    float v = __expf(2.0f * acc[m][n][e]);
                    asum += v;
                    csum[n] += v;
                }
#pragma unroll
                for (int mk = 1; mk < 16; mk <<= 1) asum += __shfl_xor(asum, mk, 64);
                if (c16 == 0) atomicAdd(&all_sum[row], asum);
            }
#pragma unroll
        for (int n = 0; n < 4; ++n) {
            float cs = csum[n];
            cs += __shfl_xor(cs, 16, 64);
            cs += __shfl_xor(cs, 32, 64);
            if (h == 0) atomicAdd(&all_sum[cbase + n * 16 + c16], cs);
        }
    }
#undef STAGE
#undef VWAIT
#undef BODY
}

__global__ __launch_bounds__(1024) void loss_kernel(const float* __restrict__ all_sum,
                                                    const float* __restrict__ pos_sum,
                                                    float* __restrict__ out) {
    const int tid = threadIdx.x;
    float s = 0.0f;
#pragma unroll
    for (int r = 0; r < 8; ++r) {
        const int i = tid + r * 1024;
        s += __logf(all_sum[i]) - __logf(pos_sum[i]);
    }
#pragma unroll
    for (int off = 32; off; off >>= 1) s += __shfl_xor(s, off, 64);
    __shared__ float red[16];
    if ((tid & 63) == 0) red[tid >> 6] = s;
    __syncthreads();
    if (tid == 0) {
        float tot = 0.f;
#pragma unroll
        for (int i = 0; i < 16; ++i) tot += red[i];
        out[0] = tot / (float)NROW;
    }
}

extern "C" void kernel_launch(void* const* d_in, const int* in_sizes, int n_in,
                              void* d_out, int out_size, void* d_ws, size_t ws_size,
                              hipStream_t stream) {
    const float* f = (const float*)d_in[0];
    float* out = (float*)d_out;

    float*  all_sum = (float*)d_ws;                    // 8192 f32
    float*  pos_sum = all_sum + NROW;                  // 8192 f32
    ushort* Hi      = (ushort*)(pos_sum + NROW);       // 8192x256 bf16, chunked
    ushort* Lo      = Hi + (size_t)NROW * DIM;

    prep_kernel<<<NROW / 32, 256, 0, stream>>>(f, Hi, Lo, all_sum);
    infonce_mfma<<<NBLK, 256, 0, stream>>>(Hi, Lo, all_sum, pos_sum);
    loss_kernel<<<1, 1024, 0, stream>>>(all_sum, pos_sum, out);
}